// Round 6
// baseline (142.364 us; speedup 1.0000x reference)
//
#include <hip/hip_runtime.h>
#include <hip/hip_bf16.h>

// B=64, T=1024, H=512, M=256
// outputs: h_new (64x512) | ctx (64x512) | align (64x1024), all fp32

typedef __attribute__((ext_vector_type(8))) __bf16 bf16x8;
typedef __attribute__((ext_vector_type(8))) unsigned short u16x8;
typedef __attribute__((ext_vector_type(4))) float f32x4;

__device__ __forceinline__ unsigned short f2bf(float f) {
    __hip_bfloat16 h = __float2bfloat16(f);
    return __builtin_bit_cast(unsigned short, h);
}
__device__ __forceinline__ float tanh_fast(float x) {
    float e = __expf(2.0f * x);
    return 1.0f - 2.0f / (e + 1.0f);   // safe at +/-inf
}
__device__ __forceinline__ float sigmoid_f(float x) {
    return 1.0f / (1.0f + __expf(-x));
}

// ---------------------------------------------------------------------------
// Fragment-major bf16 weight conversion for all 4 weight matrices.
// dst[cb*512 + l*8 + e] = bf16( src[(NB*16 + (l&15))*K + kt*32 + (l>>4)*8 + e] )
// cb local = NB*ktN + kt.
__global__ __launch_bounds__(256) void wconv_kernel(
    const float* __restrict__ W_ih, const float* __restrict__ W_hh,
    const float* __restrict__ Wq, const float* __restrict__ Wa,
    unsigned short* __restrict__ WihB, unsigned short* __restrict__ WhhB,
    unsigned short* __restrict__ WqB, unsigned short* __restrict__ WaB)
{
    const int cb = blockIdx.x * 4 + (threadIdx.x >> 6);
    const int l = threadIdx.x & 63;
    const float* src;
    unsigned short* dst;
    int K, local, NB, kt;
    if (cb < 2304) {
        src = W_ih; dst = WihB; K = 768; local = cb;
        NB = local / 24; kt = local % 24;
    } else if (cb < 3840) {
        src = W_hh; dst = WhhB; K = 512; local = cb - 2304;
        NB = local >> 4; kt = local & 15;
    } else if (cb < 4352) {
        src = Wq; dst = WqB; K = 512; local = cb - 3840;
        NB = local >> 4; kt = local & 15;
    } else {
        src = Wa; dst = WaB; K = 512; local = cb - 4352;
        NB = local >> 4; kt = local & 15;
    }
    const float* s = src + (size_t)(NB * 16 + (l & 15)) * K + kt * 32 + (l >> 4) * 8;
    float4 f0 = *(const float4*)s;
    float4 f1 = *(const float4*)(s + 4);
    u16x8 p;
    p[0] = f2bf(f0.x); p[1] = f2bf(f0.y); p[2] = f2bf(f0.z); p[3] = f2bf(f0.w);
    p[4] = f2bf(f1.x); p[5] = f2bf(f1.y); p[6] = f2bf(f1.z); p[7] = f2bf(f1.w);
    *(u16x8*)&dst[(size_t)local * 512 + l * 8] = p;
}

#define CVT8(f0, f1, AF)                                                           \
    {                                                                              \
        u16x8 p_;                                                                  \
        p_[0] = f2bf((f0).x); p_[1] = f2bf((f0).y); p_[2] = f2bf((f0).z); p_[3] = f2bf((f0).w); \
        p_[4] = f2bf((f1).x); p_[5] = f2bf((f1).y); p_[6] = f2bf((f1).z); p_[7] = f2bf((f1).w); \
        AF = __builtin_bit_cast(bf16x8, p_);                                       \
    }

// ---------------------------------------------------------------------------
// GRU step, fully fused: one wave per (16 batch rows x 16 h cols).
__global__ __launch_bounds__(64) void gru_kernel(
    const float* __restrict__ memory, const float* __restrict__ context,
    const float* __restrict__ rnn_state,
    const unsigned short* __restrict__ WihB, const float* __restrict__ b_ih,
    const unsigned short* __restrict__ WhhB, const float* __restrict__ b_hh,
    float* __restrict__ h_new)
{
    const int l = threadIdx.x;
    const int mt = blockIdx.x >> 5;     // 0..3 batch tile
    const int hb = blockIdx.x & 31;     // 0..31 h col tile
    const int r = l & 15, g = l >> 4;
    const int row = mt * 16 + r;

    f32x4 a_ir = {0,0,0,0}, a_iz = {0,0,0,0}, a_in = {0,0,0,0};
    f32x4 a_hr = {0,0,0,0}, a_hz = {0,0,0,0}, a_hn = {0,0,0,0};

#pragma unroll
    for (int kt = 0; kt < 8; ++kt) {
        const float* s = memory + (size_t)row * 256 + kt * 32 + g * 8;
        float4 f0 = *(const float4*)s, f1 = *(const float4*)(s + 4);
        bf16x8 af; CVT8(f0, f1, af);
        bf16x8 b0 = __builtin_bit_cast(bf16x8, *(const u16x8*)&WihB[((size_t)(hb) * 24 + kt) * 512 + l * 8]);
        bf16x8 b1 = __builtin_bit_cast(bf16x8, *(const u16x8*)&WihB[((size_t)(32 + hb) * 24 + kt) * 512 + l * 8]);
        bf16x8 b2 = __builtin_bit_cast(bf16x8, *(const u16x8*)&WihB[((size_t)(64 + hb) * 24 + kt) * 512 + l * 8]);
        a_ir = __builtin_amdgcn_mfma_f32_16x16x32_bf16(af, b0, a_ir, 0, 0, 0);
        a_iz = __builtin_amdgcn_mfma_f32_16x16x32_bf16(af, b1, a_iz, 0, 0, 0);
        a_in = __builtin_amdgcn_mfma_f32_16x16x32_bf16(af, b2, a_in, 0, 0, 0);
    }
#pragma unroll
    for (int kt = 8; kt < 24; ++kt) {
        const float* s = context + (size_t)row * 512 + (kt - 8) * 32 + g * 8;
        float4 f0 = *(const float4*)s, f1 = *(const float4*)(s + 4);
        bf16x8 af; CVT8(f0, f1, af);
        bf16x8 b0 = __builtin_bit_cast(bf16x8, *(const u16x8*)&WihB[((size_t)(hb) * 24 + kt) * 512 + l * 8]);
        bf16x8 b1 = __builtin_bit_cast(bf16x8, *(const u16x8*)&WihB[((size_t)(32 + hb) * 24 + kt) * 512 + l * 8]);
        bf16x8 b2 = __builtin_bit_cast(bf16x8, *(const u16x8*)&WihB[((size_t)(64 + hb) * 24 + kt) * 512 + l * 8]);
        a_ir = __builtin_amdgcn_mfma_f32_16x16x32_bf16(af, b0, a_ir, 0, 0, 0);
        a_iz = __builtin_amdgcn_mfma_f32_16x16x32_bf16(af, b1, a_iz, 0, 0, 0);
        a_in = __builtin_amdgcn_mfma_f32_16x16x32_bf16(af, b2, a_in, 0, 0, 0);
    }
#pragma unroll
    for (int kt = 0; kt < 16; ++kt) {
        const float* s = rnn_state + (size_t)row * 512 + kt * 32 + g * 8;
        float4 f0 = *(const float4*)s, f1 = *(const float4*)(s + 4);
        bf16x8 af; CVT8(f0, f1, af);
        bf16x8 b0 = __builtin_bit_cast(bf16x8, *(const u16x8*)&WhhB[((size_t)(hb) * 16 + kt) * 512 + l * 8]);
        bf16x8 b1 = __builtin_bit_cast(bf16x8, *(const u16x8*)&WhhB[((size_t)(32 + hb) * 16 + kt) * 512 + l * 8]);
        bf16x8 b2 = __builtin_bit_cast(bf16x8, *(const u16x8*)&WhhB[((size_t)(64 + hb) * 16 + kt) * 512 + l * 8]);
        a_hr = __builtin_amdgcn_mfma_f32_16x16x32_bf16(af, b0, a_hr, 0, 0, 0);
        a_hz = __builtin_amdgcn_mfma_f32_16x16x32_bf16(af, b1, a_hz, 0, 0, 0);
        a_hn = __builtin_amdgcn_mfma_f32_16x16x32_bf16(af, b2, a_hn, 0, 0, 0);
    }
    const int c = hb * 16 + r;
    const float bir = b_ih[c], biz = b_ih[512 + c], bin = b_ih[1024 + c];
    const float bhr = b_hh[c], bhz = b_hh[512 + c], bhn = b_hh[1024 + c];
#pragma unroll
    for (int r2 = 0; r2 < 4; ++r2) {
        const int m = mt * 16 + g * 4 + r2;
        float rr = sigmoid_f(a_ir[r2] + bir + a_hr[r2] + bhr);
        float zz = sigmoid_f(a_iz[r2] + biz + a_hz[r2] + bhz);
        float nn = tanh_fast(a_in[r2] + bin + rr * (a_hn[r2] + bhn));
        float h0 = rnn_state[(size_t)m * 512 + c];
        h_new[(size_t)m * 512 + c] = (1.f - zz) * nn + zz * h0;
    }
}

// q = h_new @ Wq^T + bq + ba ; one wave per (16 rows x 16 cols)
__global__ __launch_bounds__(64) void pq_kernel(
    const float* __restrict__ h_new, const unsigned short* __restrict__ WqB,
    const float* __restrict__ bq, const float* __restrict__ ba,
    float* __restrict__ q)
{
    const int l = threadIdx.x;
    const int mt = blockIdx.x >> 5;
    const int hb = blockIdx.x & 31;
    const int r = l & 15, g = l >> 4;
    const int row = mt * 16 + r;
    f32x4 acc = {0,0,0,0};
#pragma unroll
    for (int kt = 0; kt < 16; ++kt) {
        const float* s = h_new + (size_t)row * 512 + kt * 32 + g * 8;
        float4 f0 = *(const float4*)s, f1 = *(const float4*)(s + 4);
        bf16x8 af; CVT8(f0, f1, af);
        bf16x8 b0 = __builtin_bit_cast(bf16x8, *(const u16x8*)&WqB[((size_t)hb * 16 + kt) * 512 + l * 8]);
        acc = __builtin_amdgcn_mfma_f32_16x16x32_bf16(af, b0, acc, 0, 0, 0);
    }
    const int c = hb * 16 + r;
    const float add = bq[c] + ba[c];
#pragma unroll
    for (int r2 = 0; r2 < 4; ++r2)
        q[(size_t)(mt * 16 + g * 4 + r2) * 512 + c] = acc[r2] + add;
}

// ---------------- fused scores kernel v6 ------------------------------------
// Persistent col-strip blocks: grid = 256 = 64 row-groups (one batch element
// each) x 4 col-strips, 1 block/CU. The 128-col x 512-K strip of WaB (128 KB)
// is loaded ONCE into LDS via global_load_lds; then 8 waves sweep 1024 rows in
// 2 passes x 64 rows/wave, A-fragments loaded global->reg fp32 (even/odd
// prefetch, cvt in-reg), B from LDS. No barriers in the sweep. Strip-partial
// rowsums go to sc4[strip][65536]; bid%8 is strip-invariant so the 4 strips of
// a row-group share an XCD L2 for the A stream.
__global__ __launch_bounds__(512, 2) void scores_kernel(
    const float* __restrict__ ann, const unsigned short* __restrict__ WaB,
    const float* __restrict__ qv, const float* __restrict__ v,
    float* __restrict__ sc4)
{
    __shared__ unsigned short Bs[65536];   // 128 KB: 128 chunks x 64 lanes x 16B
    const int tid = threadIdx.x;
    const int l = tid & 63;
    const int w = tid >> 6;                         // wave 0..7
    const int bid = blockIdx.x;
    const int cs = (bid >> 3) & 3;                  // col strip 0..3
    const int rg = ((bid >> 5) << 3) | (bid & 7);   // row group 0..63 (== b)

    // ---- stage B strip once: local chunk = ct*16+kt, ct 0..7, kt 0..15
#pragma unroll
    for (int p = 0; p < 16; ++p) {
        int chunk = w + p * 8;                      // 0..127
        const unsigned short* gsrc =
            WaB + ((size_t)((cs * 8 + (chunk >> 4)) * 16 + (chunk & 15))) * 512 + l * 8;
        unsigned short* ldst = &Bs[chunk * 512 + l * 8];
        __builtin_amdgcn_global_load_lds(
            (const __attribute__((address_space(1))) unsigned int*)gsrc,
            (__attribute__((address_space(3))) unsigned int*)ldst, 16, 0, 0);
    }
    __syncthreads();

#define LOADA(AR, ktv)                                                                 \
    {                                                                                  \
        _Pragma("unroll")                                                              \
        for (int rt_ = 0; rt_ < 4; ++rt_) {                                            \
            const float* s_ = abase + (size_t)rt_ * (16 * 512) + (ktv) * 32;           \
            AR[rt_][0] = *(const float4*)s_;                                           \
            AR[rt_][1] = *(const float4*)(s_ + 4);                                     \
        }                                                                              \
    }

#define MFMA_K(AR, ktv)                                                                \
    {                                                                                  \
        _Pragma("unroll")                                                              \
        for (int rt_ = 0; rt_ < 4; ++rt_) {                                            \
            bf16x8 af_; CVT8(AR[rt_][0], AR[rt_][1], af_);                             \
            _Pragma("unroll")                                                          \
            for (int ct_ = 0; ct_ < 8; ++ct_) {                                        \
                bf16x8 bf_ = __builtin_bit_cast(bf16x8,                                \
                    *(const u16x8*)&Bs[(ct_ * 16 + (ktv)) * 512 + l * 8]);             \
                acc[rt_][ct_] = __builtin_amdgcn_mfma_f32_16x16x32_bf16(               \
                    af_, bf_, acc[rt_][ct_], 0, 0, 0);                                 \
            }                                                                          \
        }                                                                              \
    }

    for (int p2 = 0; p2 < 2; ++p2) {
        const int row_base = rg * 1024 + p2 * 512 + w * 64;
        const float* abase = ann + (size_t)(row_base + (l & 15)) * 512 + (l >> 4) * 8;

        f32x4 acc[4][8];
#pragma unroll
        for (int i = 0; i < 4; ++i)
#pragma unroll
            for (int j = 0; j < 8; ++j) acc[i][j] = (f32x4){0.f, 0.f, 0.f, 0.f};

        float4 aE[4][2], aO[4][2];
        LOADA(aE, 0);
        for (int kt2 = 0; kt2 < 8; ++kt2) {
            LOADA(aO, 2 * kt2 + 1);
            MFMA_K(aE, 2 * kt2);
            if (kt2 < 7) LOADA(aE, 2 * kt2 + 2);
            MFMA_K(aO, 2 * kt2 + 1);
        }

        // epilogue: partial rowsum over this strip's 128 cols of v*tanh(acc+q)
        float rsum[4][4];
#pragma unroll
        for (int i = 0; i < 4; ++i)
#pragma unroll
            for (int j = 0; j < 4; ++j) rsum[i][j] = 0.f;

#pragma unroll
        for (int ct = 0; ct < 8; ++ct) {
            int col = cs * 128 + ct * 16 + (l & 15);
            float qq = qv[rg * 512 + col];
            float vv = v[col];
#pragma unroll
            for (int rt = 0; rt < 4; ++rt) {
                f32x4 a = acc[rt][ct];
#pragma unroll
                for (int r2 = 0; r2 < 4; ++r2)
                    rsum[rt][r2] += tanh_fast(a[r2] + qq) * vv;
            }
        }
#pragma unroll
        for (int m = 1; m < 16; m <<= 1) {
#pragma unroll
            for (int rt = 0; rt < 4; ++rt)
#pragma unroll
                for (int r2 = 0; r2 < 4; ++r2)
                    rsum[rt][r2] += __shfl_xor(rsum[rt][r2], m, 64);
        }
        if ((l & 15) == 0) {
            int g = l >> 4;
#pragma unroll
            for (int rt = 0; rt < 4; ++rt)
#pragma unroll
                for (int r2 = 0; r2 < 4; ++r2)
                    sc4[(size_t)cs * 65536 + row_base + rt * 16 + g * 4 + r2] = rsum[rt][r2];
        }
    }
#undef LOADA
#undef MFMA_K
}

__global__ __launch_bounds__(256) void softmax_kernel(
    const float* __restrict__ sc4, float* __restrict__ align_)
{
    const int b = blockIdx.x, tid = threadIdx.x;
    __shared__ float red[256];
    float s[4];
#pragma unroll
    for (int j = 0; j < 4; ++j) {
        int r = b * 1024 + j * 256 + tid;
        s[j] = sc4[r] + sc4[65536 + r] + sc4[131072 + r] + sc4[196608 + r];
    }
    float mx = fmaxf(fmaxf(s[0], s[1]), fmaxf(s[2], s[3]));
    red[tid] = mx; __syncthreads();
    for (int off = 128; off > 0; off >>= 1) {
        if (tid < off) red[tid] = fmaxf(red[tid], red[tid + off]);
        __syncthreads();
    }
    mx = red[0]; __syncthreads();
    float e[4], sum = 0.f;
#pragma unroll
    for (int j = 0; j < 4; ++j) { e[j] = __expf(s[j] - mx); sum += e[j]; }
    red[tid] = sum; __syncthreads();
    for (int off = 128; off > 0; off >>= 1) {
        if (tid < off) red[tid] += red[tid + off];
        __syncthreads();
    }
    float inv = 1.0f / red[0];
#pragma unroll
    for (int j = 0; j < 4; ++j) align_[b * 1024 + j * 256 + tid] = e[j] * inv;
}

// ctx partials: block (b, tc) covers 128 rows x 512 d, float4-vectorized
__global__ __launch_bounds__(256) void ctx_part_kernel(
    const float* __restrict__ ann, const float* __restrict__ align_,
    float* __restrict__ part)
{
    const int tid = threadIdx.x;
    const int b = blockIdx.x;      // 0..63
    const int tc = blockIdx.y;     // 0..7
    __shared__ float al[128];
    __shared__ float4 red[128];
    if (tid < 128) al[tid] = align_[b * 1024 + tc * 128 + tid];
    __syncthreads();
    const int rp = tid >> 7, d4 = (tid & 127) * 4;
    const float* ap = ann + ((size_t)(b * 1024 + tc * 128)) * 512 + d4;
    float4 acc = {0.f, 0.f, 0.f, 0.f};
    for (int tt = rp; tt < 128; tt += 2) {
        float4 x = *(const float4*)(ap + (size_t)tt * 512);
        float wv = al[tt];
        acc.x += wv * x.x; acc.y += wv * x.y; acc.z += wv * x.z; acc.w += wv * x.w;
    }
    if (rp == 1) red[tid & 127] = acc;
    __syncthreads();
    if (rp == 0) {
        float4 o = red[tid];
        o.x += acc.x; o.y += acc.y; o.z += acc.z; o.w += acc.w;
        *(float4*)&part[((size_t)(tc * 64 + b)) * 512 + d4] = o;
    }
}

__global__ __launch_bounds__(256) void ctx_reduce_kernel(
    const float* __restrict__ part, float* __restrict__ ctx)
{
    int i4 = (blockIdx.x * 256 + threadIdx.x) * 4;  // < 32768
    float4 s = {0.f, 0.f, 0.f, 0.f};
#pragma unroll
    for (int p = 0; p < 8; ++p) {
        float4 x = *(const float4*)&part[(size_t)p * 32768 + i4];
        s.x += x.x; s.y += x.y; s.z += x.z; s.w += x.w;
    }
    *(float4*)&ctx[i4] = s;
}

extern "C" void kernel_launch(void* const* d_in, const int* in_sizes, int n_in,
                              void* d_out, int out_size, void* d_ws, size_t ws_size,
                              hipStream_t stream)
{
    (void)in_sizes; (void)n_in; (void)out_size; (void)ws_size;
    const float* memory    = (const float*)d_in[0];
    const float* context   = (const float*)d_in[1];
    const float* rnn_state = (const float*)d_in[2];
    const float* ann       = (const float*)d_in[3];
    const float* W_ih      = (const float*)d_in[4];
    const float* b_ih      = (const float*)d_in[5];
    const float* W_hh      = (const float*)d_in[6];
    const float* b_hh      = (const float*)d_in[7];
    const float* Wq        = (const float*)d_in[8];
    const float* bq        = (const float*)d_in[9];
    const float* Wa        = (const float*)d_in[10];
    const float* ba        = (const float*)d_in[11];
    const float* v         = (const float*)d_in[12];

    float* out    = (float*)d_out;
    float* h_new  = out;               // 32768
    float* ctx    = out + 32768;       // 32768
    float* align_ = out + 65536;       // 65536

    char* wsb = (char*)d_ws;
    float* q    = (float*)(wsb + 0);          // 128 KB
    float* sc4  = (float*)(wsb + 131072);     // 1 MB: 4 strips x 65536 fp32
    float* part = (float*)(wsb + 1179648);    // 1 MB
    unsigned short* WihB = (unsigned short*)(wsb + 2228224);  // 2.25 MB
    unsigned short* WhhB = (unsigned short*)(wsb + 4587520);  // 1.5 MB
    unsigned short* WqB  = (unsigned short*)(wsb + 6160384);  // 0.5 MB
    unsigned short* WaB  = (unsigned short*)(wsb + 6684672);  // 0.5 MB

    wconv_kernel<<<dim3(1216), dim3(256), 0, stream>>>(
        W_ih, W_hh, Wq, Wa, WihB, WhhB, WqB, WaB);
    gru_kernel<<<dim3(128), dim3(64), 0, stream>>>(
        memory, context, rnn_state, WihB, b_ih, WhhB, b_hh, h_new);
    pq_kernel<<<dim3(128), dim3(64), 0, stream>>>(h_new, WqB, bq, ba, q);
    scores_kernel<<<dim3(256), dim3(512), 0, stream>>>(ann, WaB, q, v, sc4);
    softmax_kernel<<<dim3(64), dim3(256), 0, stream>>>(sc4, align_);
    ctx_part_kernel<<<dim3(64, 8), dim3(256), 0, stream>>>(ann, align_, part);
    ctx_reduce_kernel<<<dim3(32), dim3(256), 0, stream>>>(part, ctx);
}

// Round 7
// 114.435 us; speedup vs baseline: 1.2441x; 1.2441x over previous
//
#include <hip/hip_runtime.h>
#include <hip/hip_bf16.h>

// B=64, T=1024, H=512, M=256
// outputs: h_new (64x512) | ctx (64x512) | align (64x1024), all fp32

typedef __attribute__((ext_vector_type(8))) __bf16 bf16x8;
typedef __attribute__((ext_vector_type(8))) unsigned short u16x8;
typedef __attribute__((ext_vector_type(4))) float f32x4;

__device__ __forceinline__ unsigned short f2bf(float f) {
    __hip_bfloat16 h = __float2bfloat16(f);
    return __builtin_bit_cast(unsigned short, h);
}
__device__ __forceinline__ float tanh_fast(float x) {
    float e = __expf(2.0f * x);
    return 1.0f - 2.0f / (e + 1.0f);   // safe at +/-inf
}
__device__ __forceinline__ float sigmoid_f(float x) {
    return 1.0f / (1.0f + __expf(-x));
}
// LDS byte-address swizzle: XOR bank bits 4-6 with bits 8-10.
__device__ __forceinline__ int swz(int x) { return x ^ (((x >> 8) & 7) << 4); }

// ---------------------------------------------------------------------------
// Fragment-major bf16 weight conversion for all 4 weight matrices.
// dst[cb*512 + l*8 + e] = bf16( src[(NB*16 + (l&15))*K + kt*32 + (l>>4)*8 + e] )
// cb local = NB*ktN + kt.
__global__ __launch_bounds__(256) void wconv_kernel(
    const float* __restrict__ W_ih, const float* __restrict__ W_hh,
    const float* __restrict__ Wq, const float* __restrict__ Wa,
    unsigned short* __restrict__ WihB, unsigned short* __restrict__ WhhB,
    unsigned short* __restrict__ WqB, unsigned short* __restrict__ WaB)
{
    const int cb = blockIdx.x * 4 + (threadIdx.x >> 6);
    const int l = threadIdx.x & 63;
    const float* src;
    unsigned short* dst;
    int K, local, NB, kt;
    if (cb < 2304) {
        src = W_ih; dst = WihB; K = 768; local = cb;
        NB = local / 24; kt = local % 24;
    } else if (cb < 3840) {
        src = W_hh; dst = WhhB; K = 512; local = cb - 2304;
        NB = local >> 4; kt = local & 15;
    } else if (cb < 4352) {
        src = Wq; dst = WqB; K = 512; local = cb - 3840;
        NB = local >> 4; kt = local & 15;
    } else {
        src = Wa; dst = WaB; K = 512; local = cb - 4352;
        NB = local >> 4; kt = local & 15;
    }
    const float* s = src + (size_t)(NB * 16 + (l & 15)) * K + kt * 32 + (l >> 4) * 8;
    float4 f0 = *(const float4*)s;
    float4 f1 = *(const float4*)(s + 4);
    u16x8 p;
    p[0] = f2bf(f0.x); p[1] = f2bf(f0.y); p[2] = f2bf(f0.z); p[3] = f2bf(f0.w);
    p[4] = f2bf(f1.x); p[5] = f2bf(f1.y); p[6] = f2bf(f1.z); p[7] = f2bf(f1.w);
    *(u16x8*)&dst[(size_t)local * 512 + l * 8] = p;
}

#define CVT8(f0, f1, AF)                                                           \
    {                                                                              \
        u16x8 p_;                                                                  \
        p_[0] = f2bf((f0).x); p_[1] = f2bf((f0).y); p_[2] = f2bf((f0).z); p_[3] = f2bf((f0).w); \
        p_[4] = f2bf((f1).x); p_[5] = f2bf((f1).y); p_[6] = f2bf((f1).z); p_[7] = f2bf((f1).w); \
        AF = __builtin_bit_cast(bf16x8, p_);                                       \
    }

// ---------------------------------------------------------------------------
// GRU step, fully fused: one wave per (16 batch rows x 16 h cols).
__global__ __launch_bounds__(64) void gru_kernel(
    const float* __restrict__ memory, const float* __restrict__ context,
    const float* __restrict__ rnn_state,
    const unsigned short* __restrict__ WihB, const float* __restrict__ b_ih,
    const unsigned short* __restrict__ WhhB, const float* __restrict__ b_hh,
    float* __restrict__ h_new)
{
    const int l = threadIdx.x;
    const int mt = blockIdx.x >> 5;     // 0..3 batch tile
    const int hb = blockIdx.x & 31;     // 0..31 h col tile
    const int r = l & 15, g = l >> 4;
    const int row = mt * 16 + r;

    f32x4 a_ir = {0,0,0,0}, a_iz = {0,0,0,0}, a_in = {0,0,0,0};
    f32x4 a_hr = {0,0,0,0}, a_hz = {0,0,0,0}, a_hn = {0,0,0,0};

#pragma unroll
    for (int kt = 0; kt < 8; ++kt) {
        const float* s = memory + (size_t)row * 256 + kt * 32 + g * 8;
        float4 f0 = *(const float4*)s, f1 = *(const float4*)(s + 4);
        bf16x8 af; CVT8(f0, f1, af);
        bf16x8 b0 = __builtin_bit_cast(bf16x8, *(const u16x8*)&WihB[((size_t)(hb) * 24 + kt) * 512 + l * 8]);
        bf16x8 b1 = __builtin_bit_cast(bf16x8, *(const u16x8*)&WihB[((size_t)(32 + hb) * 24 + kt) * 512 + l * 8]);
        bf16x8 b2 = __builtin_bit_cast(bf16x8, *(const u16x8*)&WihB[((size_t)(64 + hb) * 24 + kt) * 512 + l * 8]);
        a_ir = __builtin_amdgcn_mfma_f32_16x16x32_bf16(af, b0, a_ir, 0, 0, 0);
        a_iz = __builtin_amdgcn_mfma_f32_16x16x32_bf16(af, b1, a_iz, 0, 0, 0);
        a_in = __builtin_amdgcn_mfma_f32_16x16x32_bf16(af, b2, a_in, 0, 0, 0);
    }
#pragma unroll
    for (int kt = 8; kt < 24; ++kt) {
        const float* s = context + (size_t)row * 512 + (kt - 8) * 32 + g * 8;
        float4 f0 = *(const float4*)s, f1 = *(const float4*)(s + 4);
        bf16x8 af; CVT8(f0, f1, af);
        bf16x8 b0 = __builtin_bit_cast(bf16x8, *(const u16x8*)&WihB[((size_t)(hb) * 24 + kt) * 512 + l * 8]);
        bf16x8 b1 = __builtin_bit_cast(bf16x8, *(const u16x8*)&WihB[((size_t)(32 + hb) * 24 + kt) * 512 + l * 8]);
        bf16x8 b2 = __builtin_bit_cast(bf16x8, *(const u16x8*)&WihB[((size_t)(64 + hb) * 24 + kt) * 512 + l * 8]);
        a_ir = __builtin_amdgcn_mfma_f32_16x16x32_bf16(af, b0, a_ir, 0, 0, 0);
        a_iz = __builtin_amdgcn_mfma_f32_16x16x32_bf16(af, b1, a_iz, 0, 0, 0);
        a_in = __builtin_amdgcn_mfma_f32_16x16x32_bf16(af, b2, a_in, 0, 0, 0);
    }
#pragma unroll
    for (int kt = 0; kt < 16; ++kt) {
        const float* s = rnn_state + (size_t)row * 512 + kt * 32 + g * 8;
        float4 f0 = *(const float4*)s, f1 = *(const float4*)(s + 4);
        bf16x8 af; CVT8(f0, f1, af);
        bf16x8 b0 = __builtin_bit_cast(bf16x8, *(const u16x8*)&WhhB[((size_t)(hb) * 16 + kt) * 512 + l * 8]);
        bf16x8 b1 = __builtin_bit_cast(bf16x8, *(const u16x8*)&WhhB[((size_t)(32 + hb) * 16 + kt) * 512 + l * 8]);
        bf16x8 b2 = __builtin_bit_cast(bf16x8, *(const u16x8*)&WhhB[((size_t)(64 + hb) * 16 + kt) * 512 + l * 8]);
        a_hr = __builtin_amdgcn_mfma_f32_16x16x32_bf16(af, b0, a_hr, 0, 0, 0);
        a_hz = __builtin_amdgcn_mfma_f32_16x16x32_bf16(af, b1, a_hz, 0, 0, 0);
        a_hn = __builtin_amdgcn_mfma_f32_16x16x32_bf16(af, b2, a_hn, 0, 0, 0);
    }
    const int c = hb * 16 + r;
    const float bir = b_ih[c], biz = b_ih[512 + c], bin = b_ih[1024 + c];
    const float bhr = b_hh[c], bhz = b_hh[512 + c], bhn = b_hh[1024 + c];
#pragma unroll
    for (int r2 = 0; r2 < 4; ++r2) {
        const int m = mt * 16 + g * 4 + r2;
        float rr = sigmoid_f(a_ir[r2] + bir + a_hr[r2] + bhr);
        float zz = sigmoid_f(a_iz[r2] + biz + a_hz[r2] + bhz);
        float nn = tanh_fast(a_in[r2] + bin + rr * (a_hn[r2] + bhn));
        float h0 = rnn_state[(size_t)m * 512 + c];
        h_new[(size_t)m * 512 + c] = (1.f - zz) * nn + zz * h0;
    }
}

// q = h_new @ Wq^T + bq + ba ; one wave per (16 rows x 16 cols)
__global__ __launch_bounds__(64) void pq_kernel(
    const float* __restrict__ h_new, const unsigned short* __restrict__ WqB,
    const float* __restrict__ bq, const float* __restrict__ ba,
    float* __restrict__ q)
{
    const int l = threadIdx.x;
    const int mt = blockIdx.x >> 5;
    const int hb = blockIdx.x & 31;
    const int r = l & 15, g = l >> 4;
    const int row = mt * 16 + r;
    f32x4 acc = {0,0,0,0};
#pragma unroll
    for (int kt = 0; kt < 16; ++kt) {
        const float* s = h_new + (size_t)row * 512 + kt * 32 + g * 8;
        float4 f0 = *(const float4*)s, f1 = *(const float4*)(s + 4);
        bf16x8 af; CVT8(f0, f1, af);
        bf16x8 b0 = __builtin_bit_cast(bf16x8, *(const u16x8*)&WqB[((size_t)hb * 16 + kt) * 512 + l * 8]);
        acc = __builtin_amdgcn_mfma_f32_16x16x32_bf16(af, b0, acc, 0, 0, 0);
    }
    const int c = hb * 16 + r;
    const float add = bq[c] + ba[c];
#pragma unroll
    for (int r2 = 0; r2 < 4; ++r2)
        q[(size_t)(mt * 16 + g * 4 + r2) * 512 + c] = acc[r2] + add;
}

// ---------------- fused scores kernel v7 ------------------------------------
// Scheme Y, R=128: 512 thr (8 waves: 2 wave-rows x 4 wave-cols), 128 ann rows
// x 512 cols per block. A staged ONCE to LDS (bf16 frag-major, XOR-swizzled),
// with BATCHED staging loads (8-deep HBM pipelining). B (shared 512 KB WaB)
// streams coalesced from L2 with even/odd register prefetch. Zero barriers in
// the main loop. Epilogue q/v values preloaded before the main loop.
__global__ __launch_bounds__(512, 1) void scores_kernel(
    const float* __restrict__ ann, const unsigned short* __restrict__ WaB,
    const float* __restrict__ qv, const float* __restrict__ v,
    float* __restrict__ scores)
{
    __shared__ unsigned short As[65536];   // 128 KB: 128 chunks x 64 lanes x 16B
    __shared__ float s_sc[128];
    const int tid = threadIdx.x;
    const int l = tid & 63;
    const int w = tid >> 6;               // 0..7
    const int wr = w >> 2;                // wave-row 0..1 (rows wr*64..+64)
    const int wc = w & 3;                 // wave-col 0..3 (cols wc*128..+128)
    const int r0 = blockIdx.x * 128;
    const int b = blockIdx.x >> 3;

    if (tid < 128) s_sc[tid] = 0.f;

    // ---- stage A tile: 128 rows x 512 fp32 -> bf16 frag-major swizzled LDS.
    // Batched: issue 8 iterations' loads, then cvt+write, twice.
    // chunk (rtg*16+kt) in [0,128) x lane l x 8 bf16;
    // element: A[rtg*16+(l&15)][kt*32+(l>>4)*8 + e]
#pragma unroll
    for (int h = 0; h < 2; ++h) {
        float4 f[8][2];
#pragma unroll
        for (int p = 0; p < 8; ++p) {
            int cidx = tid + (h * 8 + p) * 512;   // [0,8192) 8-float chunks
            const float* s = ann + (size_t)(r0 + (cidx >> 6)) * 512 + (cidx & 63) * 8;
            f[p][0] = *(const float4*)s;
            f[p][1] = *(const float4*)(s + 4);
        }
#pragma unroll
        for (int p = 0; p < 8; ++p) {
            int cidx = tid + (h * 8 + p) * 512;
            int row = cidx >> 6;                  // 0..127
            int c8 = cidx & 63;
            int kt = c8 >> 2, g = c8 & 3;
            int rtg = row >> 4, r15 = row & 15;
            u16x8 pk;
            pk[0] = f2bf(f[p][0].x); pk[1] = f2bf(f[p][0].y);
            pk[2] = f2bf(f[p][0].z); pk[3] = f2bf(f[p][0].w);
            pk[4] = f2bf(f[p][1].x); pk[5] = f2bf(f[p][1].y);
            pk[6] = f2bf(f[p][1].z); pk[7] = f2bf(f[p][1].w);
            int logical = (((rtg * 16 + kt) * 64) + g * 16 + r15) * 16;
            *(u16x8*)((char*)As + swz(logical)) = pk;
        }
    }

    // preload epilogue constants while staging drains
    float qq[8], vv[8];
#pragma unroll
    for (int ct = 0; ct < 8; ++ct) {
        int col = wc * 128 + ct * 16 + (l & 15);
        qq[ct] = qv[b * 512 + col];
        vv[ct] = v[col];
    }
    __syncthreads();

    f32x4 acc[4][8];
#pragma unroll
    for (int i = 0; i < 4; ++i)
#pragma unroll
        for (int j = 0; j < 8; ++j) acc[i][j] = (f32x4){0.f, 0.f, 0.f, 0.f};

#define LOADB(BV, ktv)                                                                 \
    {                                                                                  \
        _Pragma("unroll")                                                              \
        for (int ct_ = 0; ct_ < 8; ++ct_)                                              \
            BV[ct_] = *(const u16x8*)(WaB +                                            \
                ((size_t)((wc * 8 + ct_) * 16 + (ktv))) * 512 + l * 8);                \
    }

#define MFMA_K(ktv, BV)                                                                \
    {                                                                                  \
        _Pragma("unroll")                                                              \
        for (int rt_ = 0; rt_ < 4; ++rt_) {                                            \
            int logical = (((wr * 4 + rt_) * 16 + (ktv)) * 64 + l) * 16;               \
            bf16x8 af_ = __builtin_bit_cast(bf16x8,                                    \
                *(const u16x8*)((char*)As + swz(logical)));                            \
            _Pragma("unroll")                                                          \
            for (int ct_ = 0; ct_ < 8; ++ct_)                                          \
                acc[rt_][ct_] = __builtin_amdgcn_mfma_f32_16x16x32_bf16(               \
                    af_, __builtin_bit_cast(bf16x8, BV[ct_]), acc[rt_][ct_], 0, 0, 0); \
        }                                                                              \
    }

    u16x8 bvE[8], bvO[8];
    LOADB(bvE, 0);
    for (int kt2 = 0; kt2 < 8; ++kt2) {
        LOADB(bvO, 2 * kt2 + 1);
        MFMA_K(2 * kt2, bvE);
        if (kt2 < 7) LOADB(bvE, 2 * kt2 + 2);
        MFMA_K(2 * kt2 + 1, bvO);
    }
#undef LOADB
#undef MFMA_K

    // epilogue: rsum[rt][r2] = sum over this wave's 128 cols of v*tanh(acc+q)
    float rsum[4][4];
#pragma unroll
    for (int i = 0; i < 4; ++i)
#pragma unroll
        for (int j = 0; j < 4; ++j) rsum[i][j] = 0.f;

#pragma unroll
    for (int ct = 0; ct < 8; ++ct) {
#pragma unroll
        for (int rt = 0; rt < 4; ++rt) {
            f32x4 a = acc[rt][ct];
#pragma unroll
            for (int r2 = 0; r2 < 4; ++r2)
                rsum[rt][r2] += tanh_fast(a[r2] + qq[ct]) * vv[ct];
        }
    }
#pragma unroll
    for (int m = 1; m < 16; m <<= 1) {
#pragma unroll
        for (int rt = 0; rt < 4; ++rt)
#pragma unroll
            for (int r2 = 0; r2 < 4; ++r2)
                rsum[rt][r2] += __shfl_xor(rsum[rt][r2], m, 64);
    }
    if ((l & 15) == 0) {
        int g = l >> 4;
#pragma unroll
        for (int rt = 0; rt < 4; ++rt)
#pragma unroll
            for (int r2 = 0; r2 < 4; ++r2)
                atomicAdd(&s_sc[wr * 64 + rt * 16 + g * 4 + r2], rsum[rt][r2]);
    }
    __syncthreads();
    if (tid < 128) scores[r0 + tid] = s_sc[tid];
}

__global__ __launch_bounds__(256) void softmax_kernel(
    const float* __restrict__ scores, float* __restrict__ align_)
{
    const int b = blockIdx.x, tid = threadIdx.x;
    __shared__ float red[256];
    float s[4];
#pragma unroll
    for (int j = 0; j < 4; ++j) s[j] = scores[b * 1024 + j * 256 + tid];
    float mx = fmaxf(fmaxf(s[0], s[1]), fmaxf(s[2], s[3]));
    red[tid] = mx; __syncthreads();
    for (int off = 128; off > 0; off >>= 1) {
        if (tid < off) red[tid] = fmaxf(red[tid], red[tid + off]);
        __syncthreads();
    }
    mx = red[0]; __syncthreads();
    float e[4], sum = 0.f;
#pragma unroll
    for (int j = 0; j < 4; ++j) { e[j] = __expf(s[j] - mx); sum += e[j]; }
    red[tid] = sum; __syncthreads();
    for (int off = 128; off > 0; off >>= 1) {
        if (tid < off) red[tid] += red[tid + off];
        __syncthreads();
    }
    float inv = 1.0f / red[0];
#pragma unroll
    for (int j = 0; j < 4; ++j) align_[b * 1024 + j * 256 + tid] = e[j] * inv;
}

// ctx partials: block (b, tc) covers 128 rows x 512 d, float4-vectorized
__global__ __launch_bounds__(256) void ctx_part_kernel(
    const float* __restrict__ ann, const float* __restrict__ align_,
    float* __restrict__ part)
{
    const int tid = threadIdx.x;
    const int b = blockIdx.x;      // 0..63
    const int tc = blockIdx.y;     // 0..7
    __shared__ float al[128];
    __shared__ float4 red[128];
    if (tid < 128) al[tid] = align_[b * 1024 + tc * 128 + tid];
    __syncthreads();
    const int rp = tid >> 7, d4 = (tid & 127) * 4;
    const float* ap = ann + ((size_t)(b * 1024 + tc * 128)) * 512 + d4;
    float4 acc = {0.f, 0.f, 0.f, 0.f};
    for (int tt = rp; tt < 128; tt += 2) {
        float4 x = *(const float4*)(ap + (size_t)tt * 512);
        float wv = al[tt];
        acc.x += wv * x.x; acc.y += wv * x.y; acc.z += wv * x.z; acc.w += wv * x.w;
    }
    if (rp == 1) red[tid & 127] = acc;
    __syncthreads();
    if (rp == 0) {
        float4 o = red[tid];
        o.x += acc.x; o.y += acc.y; o.z += acc.z; o.w += acc.w;
        *(float4*)&part[((size_t)(tc * 64 + b)) * 512 + d4] = o;
    }
}

__global__ __launch_bounds__(256) void ctx_reduce_kernel(
    const float* __restrict__ part, float* __restrict__ ctx)
{
    int i4 = (blockIdx.x * 256 + threadIdx.x) * 4;  // < 32768
    float4 s = {0.f, 0.f, 0.f, 0.f};
#pragma unroll
    for (int p = 0; p < 8; ++p) {
        float4 x = *(const float4*)&part[(size_t)p * 32768 + i4];
        s.x += x.x; s.y += x.y; s.z += x.z; s.w += x.w;
    }
    *(float4*)&ctx[i4] = s;
}

extern "C" void kernel_launch(void* const* d_in, const int* in_sizes, int n_in,
                              void* d_out, int out_size, void* d_ws, size_t ws_size,
                              hipStream_t stream)
{
    (void)in_sizes; (void)n_in; (void)out_size; (void)ws_size;
    const float* memory    = (const float*)d_in[0];
    const float* context   = (const float*)d_in[1];
    const float* rnn_state = (const float*)d_in[2];
    const float* ann       = (const float*)d_in[3];
    const float* W_ih      = (const float*)d_in[4];
    const float* b_ih      = (const float*)d_in[5];
    const float* W_hh      = (const float*)d_in[6];
    const float* b_hh      = (const float*)d_in[7];
    const float* Wq        = (const float*)d_in[8];
    const float* bq        = (const float*)d_in[9];
    const float* Wa        = (const float*)d_in[10];
    const float* ba        = (const float*)d_in[11];
    const float* v         = (const float*)d_in[12];

    float* out    = (float*)d_out;
    float* h_new  = out;               // 32768
    float* ctx    = out + 32768;       // 32768
    float* align_ = out + 65536;       // 65536

    char* wsb = (char*)d_ws;
    float* q    = (float*)(wsb + 0);          // 128 KB
    float* sc   = (float*)(wsb + 131072);     // 256 KB
    float* part = (float*)(wsb + 393216);     // 1 MB
    unsigned short* WihB = (unsigned short*)(wsb + 1441792);  // 2.25 MB
    unsigned short* WhhB = (unsigned short*)(wsb + 3801088);  // 1.5 MB
    unsigned short* WqB  = (unsigned short*)(wsb + 5373952);  // 0.5 MB
    unsigned short* WaB  = (unsigned short*)(wsb + 5898240);  // 0.5 MB

    wconv_kernel<<<dim3(1216), dim3(256), 0, stream>>>(
        W_ih, W_hh, Wq, Wa, WihB, WhhB, WqB, WaB);
    gru_kernel<<<dim3(128), dim3(64), 0, stream>>>(
        memory, context, rnn_state, WihB, b_ih, WhhB, b_hh, h_new);
    pq_kernel<<<dim3(128), dim3(64), 0, stream>>>(h_new, WqB, bq, ba, q);
    scores_kernel<<<dim3(512), dim3(512), 0, stream>>>(ann, WaB, q, v, sc);
    softmax_kernel<<<dim3(64), dim3(256), 0, stream>>>(sc, align_);
    ctx_part_kernel<<<dim3(64, 8), dim3(256), 0, stream>>>(ann, align_, part);
    ctx_reduce_kernel<<<dim3(32), dim3(256), 0, stream>>>(part, ctx);
}